// Round 7
// baseline (4741.957 us; speedup 1.0000x reference)
//
#include <hip/hip_runtime.h>

#define NBATCH 32
#define NPTS   100000
#define NDIM   6
#define KSEL   1024
#define BPB    8                  // blocks per batch
#define NTHREADS 1024
#define TOTT   (BPB * NTHREADS)   // 8192 threads per batch
#define PPT    13                 // ceil(NPTS / TOTT)

// Self-validating tagged-word slots: [2 parity][NBATCH][BPB][8] u64.
// Words 0..5 = (tag<<32)|{d_lo,d_hi,idx,x,y,z}; row padded to 64 B.
#define SLOT_WORDS 8

__global__ void __launch_bounds__(1024) fps_init(unsigned long long* w) {
    int i = blockIdx.x * blockDim.x + threadIdx.x;
    if (i < 2 * NBATCH * BPB * SLOT_WORDS) w[i] = 0ull;
}

__global__ void __launch_bounds__(NTHREADS, 1) fps_main(const float* __restrict__ pts,
                                                        float* __restrict__ out,
                                                        unsigned long long* __restrict__ slots)
{
#pragma clang fp contract(off)
    const int bid   = blockIdx.x;
    const int batch = bid & (NBATCH - 1);
    const int blk   = bid >> 5;             // 0..7 within batch
    const int tid   = threadIdx.x;
    const int lane  = tid & 63;
    const int wav   = tid >> 6;             // 0..15
    const int tg    = blk * NTHREADS + tid; // 0..8191 within batch

    __shared__ double rdv[16];
    __shared__ int    rii[16];
    __shared__ float  rfx[16], rfy[16], rfz[16];
    __shared__ float  lsh[3];               // broadcast winner xyz
    __shared__ int    idx_l[KSEL];          // leader (blk==0) only
    __shared__ double fr0[16], fr1[16], fr2[16];
    __shared__ double sc[4];

    const float* base = pts + (size_t)batch * NPTS * NDIM;

    // ---- point state in registers; dist in f64 (bit-exact vs numpy f64 FPS)
    float  px[PPT], py[PPT], pz[PPT];
    double pd[PPT];
#pragma unroll
    for (int k = 0; k < PPT; ++k) {
        int gi = k * TOTT + tg;
        if (gi < NPTS) {
            const float* p = base + (size_t)gi * NDIM;
            px[k] = p[0]; py[k] = p[1]; pz[k] = p[2];
            pd[k] = 1e10;
        } else {
            px[k] = 0.f; py[k] = 0.f; pz[k] = 0.f;
            pd[k] = -1.0;   // never wins (valid dists >= 0)
        }
    }

    double lx = (double)base[0], ly = (double)base[1], lz = (double)base[2]; // first = idx 0

    for (int t = 0; t < KSEL - 1; ++t) {
        const unsigned tag = (unsigned)(t + 1);
        const int par = t & 1;
        // ---- f64 distance update + thread-local argmax; carry winner xyz in registers
        double bd = -1.0; int bi = 0x7FFFFFFF;
        float bx = 0.f, by = 0.f, bz = 0.f;
#pragma unroll
        for (int k = 0; k < PPT; ++k) {
            double dx = (double)px[k] - lx;
            double dy = (double)py[k] - ly;
            double dz = (double)pz[k] - lz;
            double dd = ((dx * dx) + (dy * dy)) + (dz * dz);
            double nd = fmin(pd[k], dd);
            pd[k] = nd;
            if (nd > bd) { bd = nd; bi = k * TOTT + tg; bx = px[k]; by = py[k]; bz = pz[k]; }
        }
        // ---- wave reduce (dist desc, idx asc), carrying xyz
#pragma unroll
        for (int off = 32; off >= 1; off >>= 1) {
            double od = __shfl_xor(bd, off, 64);
            int    oi = __shfl_xor(bi, off, 64);
            float  ox = __shfl_xor(bx, off, 64);
            float  oy = __shfl_xor(by, off, 64);
            float  oz = __shfl_xor(bz, off, 64);
            if (od > bd || (od == bd && oi < bi)) { bd = od; bi = oi; bx = ox; by = oy; bz = oz; }
        }
        if (lane == 0) { rdv[wav] = bd; rii[wav] = bi; rfx[wav] = bx; rfy[wav] = by; rfz[wav] = bz; }
        __syncthreads();

        if (wav == 0) {
            // ---- block reduce over 16 wave winners (lanes 0..15; all converge to winner)
            double qd = (lane < 16) ? rdv[lane] : -2.0;
            int    qi = (lane < 16) ? rii[lane] : 0x7FFFFFFF;
            float  qx = (lane < 16) ? rfx[lane] : 0.f;
            float  qy = (lane < 16) ? rfy[lane] : 0.f;
            float  qz = (lane < 16) ? rfz[lane] : 0.f;
#pragma unroll
            for (int off = 8; off >= 1; off >>= 1) {
                double od = __shfl_xor(qd, off, 64);
                int    oi = __shfl_xor(qi, off, 64);
                float  ox = __shfl_xor(qx, off, 64);
                float  oy = __shfl_xor(qy, off, 64);
                float  oz = __shfl_xor(qz, off, 64);
                if (od > qd || (od == qd && oi < qi)) { qd = od; qi = oi; qx = ox; qy = oy; qz = oz; }
            }
            // ---- post: lanes 0..5 store self-validating tagged words (one wave-store)
            unsigned long long db = (unsigned long long)__double_as_longlong(qd);
            unsigned pay =
                (lane == 0) ? (unsigned)db :
                (lane == 1) ? (unsigned)(db >> 32) :
                (lane == 2) ? (unsigned)qi :
                (lane == 3) ? __float_as_uint(qx) :
                (lane == 4) ? __float_as_uint(qy) :
                              __float_as_uint(qz);
            unsigned long long* brow = slots + ((size_t)par * NBATCH + batch) * BPB * SLOT_WORDS;
            if (lane < 6)
                __hip_atomic_store(&brow[blk * SLOT_WORDS + lane],
                                   ((unsigned long long)tag << 32) | pay,
                                   __ATOMIC_RELAXED, __HIP_MEMORY_SCOPE_AGENT);
            // ---- poll: 48 lanes, one tagged word each; spin until every word is fresh
            const int pb = lane / 6, pw = lane - pb * 6;
            unsigned long long* ad = &brow[(lane < 48) ? (pb * SLOT_WORDS + pw) : 0];
            unsigned long long v;
            for (;;) {
                v = __hip_atomic_load(ad, __ATOMIC_RELAXED, __HIP_MEMORY_SCOPE_AGENT);
                int ok = (lane < 48) ? ((unsigned)(v >> 32) == tag) : 1;
                if (__all(ok)) break;
            }
            // ---- assemble records into lanes 0..7 via shuffles of the payload dword
            unsigned pv = (unsigned)v;
            int b6 = (lane < 8) ? lane * 6 : 0;
            unsigned lo_ = __shfl(pv, b6,     64);
            unsigned hi_ = __shfl(pv, b6 + 1, 64);
            unsigned ii_ = __shfl(pv, b6 + 2, 64);
            unsigned xx_ = __shfl(pv, b6 + 3, 64);
            unsigned yy_ = __shfl(pv, b6 + 4, 64);
            unsigned zz_ = __shfl(pv, b6 + 5, 64);
            double wd = __longlong_as_double((long long)(((unsigned long long)hi_ << 32) | lo_));
            int    wi = (int)ii_;
            float  wx = __uint_as_float(xx_), wy = __uint_as_float(yy_), wz = __uint_as_float(zz_);
            if (lane >= 8) { wd = -3.0; wi = 0x7FFFFFFF; }
#pragma unroll
            for (int off = 4; off >= 1; off >>= 1) {
                double od = __shfl_xor(wd, off, 64);
                int    oi = __shfl_xor(wi, off, 64);
                float  ox = __shfl_xor(wx, off, 64);
                float  oy = __shfl_xor(wy, off, 64);
                float  oz = __shfl_xor(wz, off, 64);
                if (od > wd || (od == wd && oi < wi)) { wd = od; wi = oi; wx = ox; wy = oy; wz = oz; }
            }
            if (lane == 0) {
                lsh[0] = wx; lsh[1] = wy; lsh[2] = wz;
                if (blk == 0) idx_l[t + 1] = wi;
            }
        }
        __syncthreads();
        lx = (double)lsh[0]; ly = (double)lsh[1]; lz = (double)lsh[2];
    }

    if (blk != 0) return;

    // ============ epilogue (leader block per batch): gather + normalize, f64 accumulation ============
    if (tid == 0) idx_l[0] = 0;
    __syncthreads();

    int si = idx_l[tid];
    const float* sp = base + (size_t)si * NDIM;
    float sx = sp[0], sy = sp[1], szv = sp[2];
    float f3 = sp[3], f4 = sp[4], f5 = sp[5];

    double rx = (double)sx, ry = (double)sy, rz = (double)szv;
#pragma unroll
    for (int off = 32; off >= 1; off >>= 1) {
        rx += __shfl_xor(rx, off, 64);
        ry += __shfl_xor(ry, off, 64);
        rz += __shfl_xor(rz, off, 64);
    }
    if (lane == 0) { fr0[wav] = rx; fr1[wav] = ry; fr2[wav] = rz; }
    __syncthreads();
    if (tid == 0) {
        double tx = 0., ty = 0., tz = 0.;
        for (int i = 0; i < 16; ++i) { tx += fr0[i]; ty += fr1[i]; tz += fr2[i]; }
        sc[0] = tx / (double)KSEL; sc[1] = ty / (double)KSEL; sc[2] = tz / (double)KSEL;
    }
    __syncthreads();
    double ax = (double)sx - sc[0], ay = (double)sy - sc[1], az = (double)szv - sc[2];
    double m = fmax(fabs(ax), fmax(fabs(ay), fabs(az)));
#pragma unroll
    for (int off = 32; off >= 1; off >>= 1) {
        double om = __shfl_xor(m, off, 64);
        m = fmax(m, om);
    }
    if (lane == 0) fr0[wav] = m;
    __syncthreads();
    if (tid == 0) {
        double mm = 0.;
        for (int i = 0; i < 16; ++i) mm = fmax(mm, fr0[i]);
        sc[3] = fmax(mm, 1e-6);
    }
    __syncthreads();
    double scale = sc[3];

    float* ob = out + ((size_t)batch * KSEL + tid) * NDIM;
    ob[0] = (float)(ax / scale);
    ob[1] = (float)(ay / scale);
    ob[2] = (float)(az / scale);
    ob[3] = f3; ob[4] = f4; ob[5] = f5;
}

extern "C" void kernel_launch(void* const* d_in, const int* in_sizes, int n_in,
                              void* d_out, int out_size, void* d_ws, size_t ws_size,
                              hipStream_t stream)
{
    const float* pts = (const float*)d_in[0];
    float* out = (float*)d_out;
    unsigned long long* slots = (unsigned long long*)d_ws;

    // re-zero tags every call: graph replays must not see stale matching tags
    hipLaunchKernelGGL(fps_init, dim3(4), dim3(1024), 0, stream, slots);

    void* args[] = { (void*)&pts, (void*)&out, (void*)&slots };
    hipLaunchCooperativeKernel((void*)fps_main, dim3(NBATCH * BPB), dim3(NTHREADS),
                               args, 0, stream);
}